// Round 10
// baseline (2322.524 us; speedup 1.0000x reference)
//
#include <hip/hip_runtime.h>

#define NSEQ 6400
#define TMAX 20
#define EMB 300
#define EMBP 320
#define HID 512
#define KL0 832   // EMBP + HID
#define KL1 1024  // HID + HID
#define NQT 84
#define NANS 30000
#define RELN (NQT * NANS)

typedef __bf16 bf16x8 __attribute__((ext_vector_type(8)));
typedef float f32x4 __attribute__((ext_vector_type(4)));
typedef unsigned short u16;

__device__ __forceinline__ u16 f2bf(float f) {
  union { float f; unsigned int i; } v; v.f = f;
  unsigned int r = v.i + 0x7fffu + ((v.i >> 16) & 1u);
  return (u16)(r >> 16);
}

// ---------- embeddings: embT[t][n][EMBP] bf16, zero-padded cols [300,320) ----------
__global__ __launch_bounds__(320) void embed_kernel(
    const int* __restrict__ opt, const float* __restrict__ Wemb, u16* __restrict__ embT) {
  int n = blockIdx.x;
  int e = threadIdx.x;
#pragma unroll 4
  for (int t = 0; t < TMAX; ++t) {
    int tok = opt[n * TMAX + t];
    float v = 0.f;
    if (e < EMB && tok != 0) v = Wemb[(size_t)tok * EMB + e];
    embT[((size_t)t * NSEQ + n) * EMBP + e] = f2bf(v);
  }
}

// ---------- weight repack to bf16, concatenated [ih | hh] along K ----------
__global__ void prep_w0(const float* __restrict__ wih, const float* __restrict__ whh,
                        u16* __restrict__ W) {
  for (int idx = blockIdx.x * blockDim.x + threadIdx.x; idx < 2048 * KL0;
       idx += gridDim.x * blockDim.x) {
    int o = idx / KL0, c = idx % KL0;
    float v;
    if (c < EMB) v = wih[o * EMB + c];
    else if (c < EMBP) v = 0.f;
    else v = whh[o * HID + (c - EMBP)];
    W[idx] = f2bf(v);
  }
}
__global__ void prep_w1(const float* __restrict__ wih, const float* __restrict__ whh,
                        u16* __restrict__ W) {
  for (int idx = blockIdx.x * blockDim.x + threadIdx.x; idx < 2048 * KL1;
       idx += gridDim.x * blockDim.x) {
    int o = idx / KL1, c = idx % KL1;
    float v = (c < HID) ? wih[o * HID + c] : whh[o * HID + (c - HID)];
    W[idx] = f2bf(v);
  }
}
__global__ void prep_bias(const float* __restrict__ a, const float* __restrict__ b,
                          float* __restrict__ o) {
  int i = blockIdx.x * blockDim.x + threadIdx.x;
  if (i < 2048) o[i] = a[i] + b[i];
}

// ---------- fused GEMM + LSTM cell step -------------------------------------------
// Tile: 128 rows x 32 hidden x 4 gates. EIGHT waves (4 row-quarters x 2 h-halves):
// wave tile = 32 rows x 16 h x 4 gates, acc[2][4], 8 MFMA/K-step. Doubles resident
// waves/CU (12 -> 24) at identical tile/traffic/pipeline -- pure TLP lever.
// 3-buffer, 2-ahead pipeline with COUNTED vmcnt; each wave stages 1 A- + 1 B-chunk.
// LDS XOR swizzle (pre-swizzled source + swizzled read) keeps ds_read conflict-free.
// c_state / hf are COLUMN-major [HID][NSEQ] for float4 epilogue access.
__global__ __launch_bounds__(512) void lstm_step(
    const u16* __restrict__ segA0, int strideA0, int K0,
    const u16* __restrict__ segA1,                 // [NSEQ][HID] bf16, h_old
    const u16* __restrict__ Wcat, int Ktot, int nK,
    const float* __restrict__ biasc,
    u16* __restrict__ h_new, float* __restrict__ c_state,
    const float* __restrict__ hf_old, float* __restrict__ hf_new,
    const int* __restrict__ lens, int t) {
  __shared__ __align__(16) u16 Atile[3][128 * 32];   // 8 KB x3
  __shared__ __align__(16) u16 Btile[3][128 * 32];   // 8 KB x3  (48 KB -> 3 blk/CU)
  const int tid = threadIdx.x;
  const int wave = tid >> 6, lane = tid & 63;
  const int l15 = lane & 15, l4 = lane >> 4;
  const int wr = wave >> 1, wc = wave & 1;           // wr 0..3 (32-row), wc 0..1 (16-h)

  // XCD-aware remap: 800 blocks, 8 XCDs -> chunk of 100 consecutive nids per XCD.
  const int orig = blockIdx.x;
  const int nid = (orig & 7) * 100 + (orig >> 3);
  const int rowBlk = (nid >> 4) * 128;
  const int hb = (nid & 15) * 32;

  // Each wave stages A-chunk `wave` (16 rows) and B-chunk `wave` (16 B-rows).
  const int jhi = lane >> 2;                          // 0..15 row within chunk
  const int lrow = wave * 16 + jhi;                   // 0..127 tile row
  const int srcslot = (lane & 3) ^ ((lrow >> 1) & 3); // pre-swizzled 16B slot
  const int offA0 = (rowBlk + lrow) * strideA0 + srcslot * 8;
  const int offA1 = (rowBlk + lrow) * HID + srcslot * 8;
  const int gB = lrow >> 5, hB = lrow & 31;
  const int offB = (gB * HID + hb + hB) * Ktot + srcslot * 8;

  auto stage = [&](int sel, int ks) {
    const int kbase = ks * 32;
    const bool s1 = kbase >= K0;
    const u16* aPtr = s1 ? (segA1 + (kbase - K0) + offA1) : (segA0 + kbase + offA0);
    __builtin_amdgcn_global_load_lds(
        (const __attribute__((address_space(1))) void*)aPtr,
        (__attribute__((address_space(3))) void*)(&Atile[sel][wave * 512]),
        16, 0, 0);
    __builtin_amdgcn_global_load_lds(
        (const __attribute__((address_space(1))) void*)(Wcat + offB + kbase),
        (__attribute__((address_space(3))) void*)(&Btile[sel][wave * 512]),
        16, 0, 0);
  };

  f32x4 acc[2][4] = {};
  const int kx = (l4 ^ ((l15 >> 1) & 3)) * 8;   // swizzled read offset (elements)

  auto compute = [&](int sel) {
    bf16x8 a[2], b[4];
#pragma unroll
    for (int m = 0; m < 2; ++m)
      a[m] = *(const bf16x8*)(&Atile[sel][(wr * 32 + m * 16 + l15) * 32 + kx]);
#pragma unroll
    for (int g = 0; g < 4; ++g)
      b[g] = *(const bf16x8*)(&Btile[sel][(g * 32 + wc * 16 + l15) * 32 + kx]);
    __builtin_amdgcn_s_setprio(1);
#pragma unroll
    for (int m = 0; m < 2; ++m)
#pragma unroll
      for (int g = 0; g < 4; ++g)
        acc[m][g] = __builtin_amdgcn_mfma_f32_16x16x32_bf16(a[m], b[g], acc[m][g], 0, 0, 0);
    __builtin_amdgcn_s_setprio(0);
  };

  // Pipeline: 2-ahead prefetch, counted vmcnt (2 loads/wave/stage -> steady vmcnt(4)).
  stage(0, 0);
  stage(1, 1);
  int sel = 0, pre = 2;
  for (int ks = 0; ks < nK; ++ks) {
    if (ks + 2 < nK) {
      stage(pre, ks + 2);
      if (++pre == 3) pre = 0;
      asm volatile("s_waitcnt vmcnt(4)" ::: "memory");
    } else if (ks + 1 < nK) {
      asm volatile("s_waitcnt vmcnt(2)" ::: "memory");
    } else {
      asm volatile("s_waitcnt vmcnt(0)" ::: "memory");
    }
    __builtin_amdgcn_s_barrier();
    compute(sel);
    if (++sel == 3) sel = 0;
    if (ks + 1 < nK) __builtin_amdgcn_s_barrier();
  }

  // epilogue: LSTM cell. C/D frag: col = lane&15, row = (lane>>4)*4 + reg
  const int u = hb + wc * 16 + l15;
  const float bi = biasc[u], bff = biasc[512 + u], bg = biasc[1024 + u], bo = biasc[1536 + u];
#pragma unroll
  for (int m = 0; m < 2; ++m) {
    const int rbase = rowBlk + wr * 32 + m * 16 + l4 * 4;
    const size_t cmi = (size_t)u * NSEQ + rbase;       // column-major index
    f32x4 co4 = *(const f32x4*)(c_state + cmi);
    int4 ln4 = *(const int4*)(lens + rbase);
    f32x4 ho4;
    if (hf_new) ho4 = *(const f32x4*)(hf_old + cmi);
    f32x4 cn4, hn4;
    u16 hstore[4];
#pragma unroll
    for (int jj = 0; jj < 4; ++jj) {
      const int r = rbase + jj;
      float ip = acc[m][0][jj] + bi;
      float fp = acc[m][1][jj] + bff;
      float gp = acc[m][2][jj] + bg;
      float op = acc[m][3][jj] + bo;
      float co = co4[jj];
      float si = 1.f / (1.f + __expf(-ip));
      float sf = 1.f / (1.f + __expf(-fp));
      float so = 1.f / (1.f + __expf(-op));
      float tg = tanhf(gp);
      float cn = sf * co + si * tg;
      float hn = so * tanhf(cn);
      int len = (jj == 0) ? ln4.x : (jj == 1) ? ln4.y : (jj == 2) ? ln4.z : ln4.w;
      bool act = t < len;
      cn4[jj] = act ? cn : co;
      hstore[jj] = act ? f2bf(hn) : segA1[(size_t)r * HID + u];
      if (hf_new) hn4[jj] = act ? hn : ho4[jj];
    }
    *(f32x4*)(c_state + cmi) = cn4;
    if (hf_new) *(f32x4*)(hf_new + cmi) = hn4;
#pragma unroll
    for (int jj = 0; jj < 4; ++jj)
      h_new[(size_t)(rbase + jj) * HID + u] = hstore[jj];
  }
}

// ---------- scores: out[n] = dot(h2[:,n] (col-major), enc[n/100,:]) ----------
__global__ __launch_bounds__(256) void scores_kernel(
    const float* __restrict__ h2cm, const float* __restrict__ enc, float* __restrict__ out) {
  int n = (blockIdx.x >> 1) * 256 + threadIdx.x;      // 25 n-blocks x 2 u-halves
  int uh = (blockIdx.x & 1) * 256;
  const float* ep = enc + (n / 100) * HID + uh;
  float s = 0.f;
#pragma unroll 8
  for (int u = 0; u < 256; ++u) s += h2cm[(size_t)(uh + u) * NSEQ + n] * ep[u];
  atomicAdd(&out[n], s);
}

// ---------- relevance dtype detection (bool may arrive as u8/i32/i64/f32) ----------
__global__ void detect_kernel(const unsigned char* __restrict__ rel, int* __restrict__ flags) {
  int a = 0, bb = 0, z = 0;
  for (int i = blockIdx.x * blockDim.x + threadIdx.x; i < RELN; i += gridDim.x * blockDim.x) {
    if (rel[i]) {
      if (i & 3) a = 1; else z = 1;
      if (i & 4) bb = 1;
    }
  }
  if (a) atomicOr(&flags[0], 1);
  if (bb) atomicOr(&flags[1], 1);
  if (z) atomicOr(&flags[2], 1);
}

__global__ void qt_kernel(const void* __restrict__ rel, const int* __restrict__ qt_idx,
                          const int* __restrict__ opt_idx, const int* __restrict__ flags,
                          float* __restrict__ out) {
  int n = blockIdx.x * blockDim.x + threadIdx.x;
  if (n >= NSEQ) return;
  long long idx = (long long)qt_idx[n / 100] * NANS + opt_idx[n];
  int fa = flags[0], fb = flags[1], fz = flags[2];
  bool hit;
  if (fa && fz)       hit = ((const unsigned char*)rel)[idx] != 0;   // uint8 bool
  else if (fa)        hit = ((const float*)rel)[idx] != 0.f;         // float32
  else if (fb)        hit = ((const int*)rel)[idx] != 0;             // int32
  else                hit = ((const long long*)rel)[idx] != 0;       // int64
  out[NSEQ + n] = hit ? 1.f : 0.f;
}

extern "C" void kernel_launch(void* const* d_in, const int* in_sizes, int n_in,
                              void* d_out, int out_size, void* d_ws, size_t ws_size,
                              hipStream_t stream) {
  (void)in_sizes; (void)n_in; (void)out_size; (void)ws_size;
  const float* enc    = (const float*)d_in[0];
  const int*   opt    = (const int*)d_in[1];
  const int*   optlen = (const int*)d_in[2];
  const int*   qtidx  = (const int*)d_in[3];
  const int*   optidx = (const int*)d_in[4];
  const float* Wemb   = (const float*)d_in[5];
  const float* wih0   = (const float*)d_in[6];
  const float* whh0   = (const float*)d_in[7];
  const float* bih0   = (const float*)d_in[8];
  const float* bhh0   = (const float*)d_in[9];
  const float* wih1   = (const float*)d_in[10];
  const float* whh1   = (const float*)d_in[11];
  const float* bih1   = (const float*)d_in[12];
  const float* bhh1   = (const float*)d_in[13];
  const void*  rel    = d_in[14];
  float* out = (float*)d_out;

  char* ws = (char*)d_ws;
  size_t off = 0;
  auto alloc = [&](size_t bytes) -> void* {
    void* p = (void*)(ws + off);
    off += (bytes + 255) & ~(size_t)255;
    return p;
  };
  u16* embT   = (u16*)alloc((size_t)TMAX * NSEQ * EMBP * 2);
  u16* W0     = (u16*)alloc((size_t)2048 * KL0 * 2);
  u16* W1     = (u16*)alloc((size_t)2048 * KL1 * 2);
  float* bc0  = (float*)alloc(2048 * 4);
  float* bc1  = (float*)alloc(2048 * 4);
  u16* h0b[2] = { (u16*)alloc((size_t)NSEQ * HID * 2), (u16*)alloc((size_t)NSEQ * HID * 2) };
  u16* h1b[2] = { (u16*)alloc((size_t)NSEQ * HID * 2), (u16*)alloc((size_t)NSEQ * HID * 2) };
  float* c0   = (float*)alloc((size_t)NSEQ * HID * 4);
  float* c1   = (float*)alloc((size_t)NSEQ * HID * 4);
  float* hf[2] = { (float*)alloc((size_t)NSEQ * HID * 4), (float*)alloc((size_t)NSEQ * HID * 4) };
  int* flags  = (int*)alloc(16);

  hipMemsetAsync(h0b[0], 0, (size_t)NSEQ * HID * 2, stream);
  hipMemsetAsync(h1b[0], 0, (size_t)NSEQ * HID * 2, stream);
  hipMemsetAsync(c0, 0, (size_t)NSEQ * HID * 4, stream);
  hipMemsetAsync(c1, 0, (size_t)NSEQ * HID * 4, stream);
  hipMemsetAsync(hf[0], 0, (size_t)NSEQ * HID * 4, stream);
  hipMemsetAsync(flags, 0, 16, stream);
  hipMemsetAsync(out, 0, (size_t)NSEQ * 4, stream);   // scores accumulated atomically

  embed_kernel<<<NSEQ, EMBP, 0, stream>>>(opt, Wemb, embT);
  prep_w0<<<512, 256, 0, stream>>>(wih0, whh0, W0);
  prep_w1<<<512, 256, 0, stream>>>(wih1, whh1, W1);
  prep_bias<<<8, 256, 0, stream>>>(bih0, bhh0, bc0);
  prep_bias<<<8, 256, 0, stream>>>(bih1, bhh1, bc1);
  detect_kernel<<<256, 256, 0, stream>>>((const unsigned char*)rel, flags);

  for (int t = 0; t < TMAX; ++t) {
    int cur = t & 1, nxt = cur ^ 1;
    // layer 0: A = [emb_t | h0], B = W0cat
    lstm_step<<<800, 512, 0, stream>>>(
        embT + (size_t)t * NSEQ * EMBP, EMBP, EMBP,
        h0b[cur], W0, KL0, KL0 / 32, bc0,
        h0b[nxt], c0, nullptr, nullptr, optlen, t);
    // layer 1: A = [h0_new | h1], B = W1cat
    lstm_step<<<800, 512, 0, stream>>>(
        h0b[nxt], HID, HID,
        h1b[cur], W1, KL1, KL1 / 32, bc1,
        h1b[nxt], c1, hf[cur], hf[nxt], optlen, t);
  }

  scores_kernel<<<50, 256, 0, stream>>>(hf[0], enc, out);
  qt_kernel<<<(NSEQ + 255) / 256, 256, 0, stream>>>(rel, qtidx, optidx, flags, out);
}

// Round 11
// 2139.230 us; speedup vs baseline: 1.0857x; 1.0857x over previous
//
#include <hip/hip_runtime.h>

#define NSEQ 6400
#define TMAX 20
#define EMB 300
#define EMBP 320
#define HID 512
#define KL0 832   // EMBP + HID  (13 x 64)
#define KL1 1024  // HID + HID   (16 x 64)
#define NQT 84
#define NANS 30000
#define RELN (NQT * NANS)

typedef __bf16 bf16x8 __attribute__((ext_vector_type(8)));
typedef float f32x4 __attribute__((ext_vector_type(4)));
typedef unsigned short u16;

__device__ __forceinline__ u16 f2bf(float f) {
  union { float f; unsigned int i; } v; v.f = f;
  unsigned int r = v.i + 0x7fffu + ((v.i >> 16) & 1u);
  return (u16)(r >> 16);
}

// ---------- embeddings: embT[t][n][EMBP] bf16, zero-padded cols [300,320) ----------
__global__ __launch_bounds__(320) void embed_kernel(
    const int* __restrict__ opt, const float* __restrict__ Wemb, u16* __restrict__ embT) {
  int n = blockIdx.x;
  int e = threadIdx.x;
#pragma unroll 4
  for (int t = 0; t < TMAX; ++t) {
    int tok = opt[n * TMAX + t];
    float v = 0.f;
    if (e < EMB && tok != 0) v = Wemb[(size_t)tok * EMB + e];
    embT[((size_t)t * NSEQ + n) * EMBP + e] = f2bf(v);
  }
}

// ---------- weight repack to bf16, concatenated [ih | hh] along K ----------
__global__ void prep_w0(const float* __restrict__ wih, const float* __restrict__ whh,
                        u16* __restrict__ W) {
  for (int idx = blockIdx.x * blockDim.x + threadIdx.x; idx < 2048 * KL0;
       idx += gridDim.x * blockDim.x) {
    int o = idx / KL0, c = idx % KL0;
    float v;
    if (c < EMB) v = wih[o * EMB + c];
    else if (c < EMBP) v = 0.f;
    else v = whh[o * HID + (c - EMBP)];
    W[idx] = f2bf(v);
  }
}
__global__ void prep_w1(const float* __restrict__ wih, const float* __restrict__ whh,
                        u16* __restrict__ W) {
  for (int idx = blockIdx.x * blockDim.x + threadIdx.x; idx < 2048 * KL1;
       idx += gridDim.x * blockDim.x) {
    int o = idx / KL1, c = idx % KL1;
    float v = (c < HID) ? wih[o * HID + c] : whh[o * HID + (c - HID)];
    W[idx] = f2bf(v);
  }
}
__global__ void prep_bias(const float* __restrict__ a, const float* __restrict__ b,
                          float* __restrict__ o) {
  int i = blockIdx.x * blockDim.x + threadIdx.x;
  if (i < 2048) o[i] = a[i] + b[i];
}

// ---------- fused GEMM + LSTM cell step: m201-style 8-phase 256x256 template ------
// BM=256 seq rows, BN=256 = 4 gates x 64 h, BK=64. 8 waves (4M x 2N); wave tile
// 64 rows x (4 gates x 32 h). Gate-major B rows [g*64+h] put all 4 gates of a given
// (row,h) IN-LANE for the fused LSTM epilogue. LDS: A[2][256][64] + B[2][256][64]
// bf16 = 128 KB, double-buffered. Per K-tile: 4 phases, each
// {ds_read subtile | 2x global_load_lds prefetch | barrier | setprio 16 MFMA | barrier};
// vmcnt(0) once per K-tile (phases are ~600+ cyc >> L2 latency). Slot-XOR swizzle
// (slot ^ row&7) applied on BOTH sides (pre-swizzled source + swizzled read).
__global__ __launch_bounds__(512, 2) void lstm_step(
    const u16* __restrict__ segA0, int strideA0, int K0,
    const u16* __restrict__ segA1,                 // [NSEQ][HID] bf16, h_old
    const u16* __restrict__ Wcat, int Ktot, int nkt,
    const float* __restrict__ biasc,
    u16* __restrict__ h_new, float* __restrict__ c_state,
    const float* __restrict__ hf_old, float* __restrict__ hf_new,
    const int* __restrict__ lens, int t) {
  __shared__ __align__(16) u16 Abuf[2][256 * 64];   // 32 KB x2
  __shared__ __align__(16) u16 Bbuf[2][256 * 64];   // 32 KB x2 -> 128 KB, 1 blk/CU
  const int tid = threadIdx.x;
  const int wave = tid >> 6, lane = tid & 63;
  const int l15 = lane & 15, l4 = lane >> 4;
  const int mw = wave >> 1, nw = wave & 1;          // mw 0..3 (64-row), nw 0..1 (32-h)

  // bijective XCD remap: 200 blocks, 8 XCDs, q=25 -> xcd gets 25 consecutive wgids
  const int orig = blockIdx.x;
  const int wgid = (orig & 7) * 25 + (orig >> 3);
  const int rowBlk = (wgid >> 3) * 256;             // 25 row tiles
  const int hblk = (wgid & 7) * 64;                 // 8 h windows

  // staging thread map: 512 thr x 16 B; per half-tile (128 rows x 64 k) 2 issues
  const int srow = tid >> 3;                        // 0..63
  const int sslot = (tid & 7) ^ (srow & 7);         // pre-swizzled source 16B slot

  auto stageA = [&](int sel, int hb, int kt) {
    const int kbase = kt * 64;
    const bool s1 = kbase >= K0;
#pragma unroll
    for (int i = 0; i < 2; ++i) {
      int lrow = hb * 128 + i * 64 + srow;
      int gr = rowBlk + lrow;
      const u16* src = s1 ? (segA1 + (size_t)gr * HID + (kbase - K0) + sslot * 8)
                          : (segA0 + (size_t)gr * strideA0 + kbase + sslot * 8);
      __builtin_amdgcn_global_load_lds(
          (const __attribute__((address_space(1))) void*)src,
          (__attribute__((address_space(3))) void*)(&Abuf[sel][lrow * 64 + (tid & 7) * 8]),
          16, 0, 0);
    }
  };
  auto stageB = [&](int sel, int hb, int kt) {
    const int kbase = kt * 64;
#pragma unroll
    for (int i = 0; i < 2; ++i) {
      int lrow = hb * 128 + i * 64 + srow;          // = g*64 + h ; g = hb*2+i, h = srow
      int g = hb * 2 + i;
      const u16* src = Wcat + (size_t)(g * HID + hblk + srow) * Ktot + kbase + sslot * 8;
      __builtin_amdgcn_global_load_lds(
          (const __attribute__((address_space(1))) void*)src,
          (__attribute__((address_space(3))) void*)(&Bbuf[sel][lrow * 64 + (tid & 7) * 8]),
          16, 0, 0);
    }
  };

  f32x4 acc[4][8] = {};   // [m-frag 0..3][nf = gate*2 + hsub]
  bf16x8 a[2][2], bLo[4][2], bHi[4][2];

  auto rdA = [&](int sel, int mhalf) {
#pragma unroll
    for (int mf = 0; mf < 2; ++mf)
#pragma unroll
      for (int ks = 0; ks < 2; ++ks) {
        int row = mw * 64 + mhalf * 32 + mf * 16 + l15;
        int q = (ks * 4 + l4) ^ (row & 7);
        a[mf][ks] = *(const bf16x8*)&Abuf[sel][row * 64 + q * 8];
      }
  };
  auto rdB = [&](int sel, int nhalf, bf16x8 b[4][2]) {
#pragma unroll
    for (int f = 0; f < 4; ++f)
#pragma unroll
      for (int ks = 0; ks < 2; ++ks) {
        int nf = nhalf * 4 + f;
        int row = (nf >> 1) * 64 + nw * 32 + (nf & 1) * 16 + l15;
        int q = (ks * 4 + l4) ^ (row & 7);
        b[f][ks] = *(const bf16x8*)&Bbuf[sel][row * 64 + q * 8];
      }
  };
  auto mma = [&](bf16x8 b[4][2], int mhalf, int nhalf) {
    __builtin_amdgcn_s_setprio(1);
#pragma unroll
    for (int mf = 0; mf < 2; ++mf)
#pragma unroll
      for (int f = 0; f < 4; ++f)
#pragma unroll
        for (int ks = 0; ks < 2; ++ks)
          acc[mhalf * 2 + mf][nhalf * 4 + f] = __builtin_amdgcn_mfma_f32_16x16x32_bf16(
              a[mf][ks], b[f][ks], acc[mhalf * 2 + mf][nhalf * 4 + f], 0, 0, 0);
    __builtin_amdgcn_s_setprio(0);
  };

  // prologue: stage K-tile 0 fully, drain, barrier
  stageA(0, 0, 0); stageA(0, 1, 0); stageB(0, 0, 0); stageB(0, 1, 0);
  asm volatile("s_waitcnt vmcnt(0)" ::: "memory");
  __builtin_amdgcn_s_barrier();

  for (int kt = 0; kt < nkt; ++kt) {
    const int cur = kt & 1, nxt = cur ^ 1;
    const bool pf = (kt + 1 < nkt);
    // p0: m_lo x n_lo
    rdA(cur, 0); rdB(cur, 0, bLo);
    if (pf) stageA(nxt, 0, kt + 1);
    __builtin_amdgcn_s_barrier();
    mma(bLo, 0, 0);
    __builtin_amdgcn_s_barrier();
    // p1: m_lo x n_hi
    rdB(cur, 1, bHi);
    if (pf) stageA(nxt, 1, kt + 1);
    __builtin_amdgcn_s_barrier();
    mma(bHi, 0, 1);
    __builtin_amdgcn_s_barrier();
    // p2: m_hi x n_hi
    rdA(cur, 1);
    if (pf) stageB(nxt, 0, kt + 1);
    __builtin_amdgcn_s_barrier();
    mma(bHi, 1, 1);
    __builtin_amdgcn_s_barrier();
    // p3: m_hi x n_lo (no new reads; reuse a-hi, bLo)
    if (pf) stageB(nxt, 1, kt + 1);
    mma(bLo, 1, 0);
    if (pf) asm volatile("s_waitcnt vmcnt(0)" ::: "memory");
    __builtin_amdgcn_s_barrier();
  }

  // epilogue: LSTM cell. acc frag: col(l15) = h-sub index, row = l4*4+jj = seq row.
  // gates of (row, hsub): i=acc[m][hs], f=acc[m][2+hs], g=acc[m][4+hs], o=acc[m][6+hs]
#pragma unroll
  for (int hs = 0; hs < 2; ++hs) {
    const int uu = hblk + nw * 32 + hs * 16 + l15;
    const float bi = biasc[uu], bff = biasc[512 + uu];
    const float bgg = biasc[1024 + uu], bo = biasc[1536 + uu];
#pragma unroll
    for (int m = 0; m < 4; ++m) {
      const int rbase = rowBlk + mw * 64 + m * 16 + l4 * 4;
      const size_t cmi = (size_t)uu * NSEQ + rbase;   // column-major state index
      f32x4 co4 = *(const f32x4*)(c_state + cmi);
      int4 ln4 = *(const int4*)(lens + rbase);
      f32x4 ho4;
      if (hf_new) ho4 = *(const f32x4*)(hf_old + cmi);
      f32x4 cn4, hn4;
      u16 hstore[4];
#pragma unroll
      for (int jj = 0; jj < 4; ++jj) {
        float ip = acc[m][hs][jj] + bi;
        float fp = acc[m][2 + hs][jj] + bff;
        float gp = acc[m][4 + hs][jj] + bgg;
        float op = acc[m][6 + hs][jj] + bo;
        float co = co4[jj];
        float si = 1.f / (1.f + __expf(-ip));
        float sf = 1.f / (1.f + __expf(-fp));
        float so = 1.f / (1.f + __expf(-op));
        float tg = tanhf(gp);
        float cn = sf * co + si * tg;
        float hn = so * tanhf(cn);
        int len = (jj == 0) ? ln4.x : (jj == 1) ? ln4.y : (jj == 2) ? ln4.z : ln4.w;
        bool act = t < len;
        cn4[jj] = act ? cn : co;
        hstore[jj] = act ? f2bf(hn) : segA1[(size_t)(rbase + jj) * HID + uu];
        if (hf_new) hn4[jj] = act ? hn : ho4[jj];
      }
      *(f32x4*)(c_state + cmi) = cn4;
      if (hf_new) *(f32x4*)(hf_new + cmi) = hn4;
#pragma unroll
      for (int jj = 0; jj < 4; ++jj)
        h_new[(size_t)(rbase + jj) * HID + uu] = hstore[jj];
    }
  }
}

// ---------- scores: out[n] = dot(h2[:,n] (col-major), enc[n/100,:]) ----------
__global__ __launch_bounds__(256) void scores_kernel(
    const float* __restrict__ h2cm, const float* __restrict__ enc, float* __restrict__ out) {
  int n = (blockIdx.x >> 1) * 256 + threadIdx.x;      // 25 n-blocks x 2 u-halves
  int uh = (blockIdx.x & 1) * 256;
  const float* ep = enc + (n / 100) * HID + uh;
  float s = 0.f;
#pragma unroll 8
  for (int u = 0; u < 256; ++u) s += h2cm[(size_t)(uh + u) * NSEQ + n] * ep[u];
  atomicAdd(&out[n], s);
}

// ---------- relevance dtype detection (bool may arrive as u8/i32/i64/f32) ----------
__global__ void detect_kernel(const unsigned char* __restrict__ rel, int* __restrict__ flags) {
  int a = 0, bb = 0, z = 0;
  for (int i = blockIdx.x * blockDim.x + threadIdx.x; i < RELN; i += gridDim.x * blockDim.x) {
    if (rel[i]) {
      if (i & 3) a = 1; else z = 1;
      if (i & 4) bb = 1;
    }
  }
  if (a) atomicOr(&flags[0], 1);
  if (bb) atomicOr(&flags[1], 1);
  if (z) atomicOr(&flags[2], 1);
}

__global__ void qt_kernel(const void* __restrict__ rel, const int* __restrict__ qt_idx,
                          const int* __restrict__ opt_idx, const int* __restrict__ flags,
                          float* __restrict__ out) {
  int n = blockIdx.x * blockDim.x + threadIdx.x;
  if (n >= NSEQ) return;
  long long idx = (long long)qt_idx[n / 100] * NANS + opt_idx[n];
  int fa = flags[0], fb = flags[1], fz = flags[2];
  bool hit;
  if (fa && fz)       hit = ((const unsigned char*)rel)[idx] != 0;   // uint8 bool
  else if (fa)        hit = ((const float*)rel)[idx] != 0.f;         // float32
  else if (fb)        hit = ((const int*)rel)[idx] != 0;             // int32
  else                hit = ((const long long*)rel)[idx] != 0;       // int64
  out[NSEQ + n] = hit ? 1.f : 0.f;
}

extern "C" void kernel_launch(void* const* d_in, const int* in_sizes, int n_in,
                              void* d_out, int out_size, void* d_ws, size_t ws_size,
                              hipStream_t stream) {
  (void)in_sizes; (void)n_in; (void)out_size; (void)ws_size;
  const float* enc    = (const float*)d_in[0];
  const int*   opt    = (const int*)d_in[1];
  const int*   optlen = (const int*)d_in[2];
  const int*   qtidx  = (const int*)d_in[3];
  const int*   optidx = (const int*)d_in[4];
  const float* Wemb   = (const float*)d_in[5];
  const float* wih0   = (const float*)d_in[6];
  const float* whh0   = (const float*)d_in[7];
  const float* bih0   = (const float*)d_in[8];
  const float* bhh0   = (const float*)d_in[9];
  const float* wih1   = (const float*)d_in[10];
  const float* whh1   = (const float*)d_in[11];
  const float* bih1   = (const float*)d_in[12];
  const float* bhh1   = (const float*)d_in[13];
  const void*  rel    = d_in[14];
  float* out = (float*)d_out;

  char* ws = (char*)d_ws;
  size_t off = 0;
  auto alloc = [&](size_t bytes) -> void* {
    void* p = (void*)(ws + off);
    off += (bytes + 255) & ~(size_t)255;
    return p;
  };
  u16* embT   = (u16*)alloc((size_t)TMAX * NSEQ * EMBP * 2);
  u16* W0     = (u16*)alloc((size_t)2048 * KL0 * 2);
  u16* W1     = (u16*)alloc((size_t)2048 * KL1 * 2);
  float* bc0  = (float*)alloc(2048 * 4);
  float* bc1  = (float*)alloc(2048 * 4);
  u16* h0b[2] = { (u16*)alloc((size_t)NSEQ * HID * 2), (u16*)alloc((size_t)NSEQ * HID * 2) };
  u16* h1b[2] = { (u16*)alloc((size_t)NSEQ * HID * 2), (u16*)alloc((size_t)NSEQ * HID * 2) };
  float* c0   = (float*)alloc((size_t)NSEQ * HID * 4);
  float* c1   = (float*)alloc((size_t)NSEQ * HID * 4);
  float* hf[2] = { (float*)alloc((size_t)NSEQ * HID * 4), (float*)alloc((size_t)NSEQ * HID * 4) };
  int* flags  = (int*)alloc(16);

  hipMemsetAsync(h0b[0], 0, (size_t)NSEQ * HID * 2, stream);
  hipMemsetAsync(h1b[0], 0, (size_t)NSEQ * HID * 2, stream);
  hipMemsetAsync(c0, 0, (size_t)NSEQ * HID * 4, stream);
  hipMemsetAsync(c1, 0, (size_t)NSEQ * HID * 4, stream);
  hipMemsetAsync(hf[0], 0, (size_t)NSEQ * HID * 4, stream);
  hipMemsetAsync(flags, 0, 16, stream);
  hipMemsetAsync(out, 0, (size_t)NSEQ * 4, stream);   // scores accumulated atomically

  embed_kernel<<<NSEQ, EMBP, 0, stream>>>(opt, Wemb, embT);
  prep_w0<<<512, 256, 0, stream>>>(wih0, whh0, W0);
  prep_w1<<<512, 256, 0, stream>>>(wih1, whh1, W1);
  prep_bias<<<8, 256, 0, stream>>>(bih0, bhh0, bc0);
  prep_bias<<<8, 256, 0, stream>>>(bih1, bhh1, bc1);
  detect_kernel<<<256, 256, 0, stream>>>((const unsigned char*)rel, flags);

  for (int t = 0; t < TMAX; ++t) {
    int cur = t & 1, nxt = cur ^ 1;
    // layer 0: A = [emb_t | h0], B = W0cat   (13 K-tiles; emb/h boundary at 320 = 5x64)
    lstm_step<<<200, 512, 0, stream>>>(
        embT + (size_t)t * NSEQ * EMBP, EMBP, EMBP,
        h0b[cur], W0, KL0, KL0 / 64, bc0,
        h0b[nxt], c0, nullptr, nullptr, optlen, t);
    // layer 1: A = [h0_new | h1], B = W1cat  (16 K-tiles; boundary at 512 = 8x64)
    lstm_step<<<200, 512, 0, stream>>>(
        h0b[nxt], HID, HID,
        h1b[cur], W1, KL1, KL1 / 64, bc1,
        h1b[nxt], c1, hf[cur], hf[nxt], optlen, t);
  }

  scores_kernel<<<50, 256, 0, stream>>>(hf[0], enc, out);
  qt_kernel<<<(NSEQ + 255) / 256, 256, 0, stream>>>(rel, qtidx, optidx, flags, out);
}

// Round 14
// 2025.971 us; speedup vs baseline: 1.1464x; 1.0559x over previous
//
#include <hip/hip_runtime.h>

#define NSEQ 6400
#define TMAX 20
#define EMB 300
#define EMBP 320
#define HID 512
#define KL0 832   // EMBP + HID  (13 x 64)
#define KL1 1024  // HID + HID   (16 x 64)
#define NQT 84
#define NANS 30000
#define RELN (NQT * NANS)

typedef __bf16 bf16x8 __attribute__((ext_vector_type(8)));
typedef float f32x4 __attribute__((ext_vector_type(4)));
typedef unsigned short u16;

__device__ __forceinline__ u16 f2bf(float f) {
  union { float f; unsigned int i; } v; v.f = f;
  unsigned int r = v.i + 0x7fffu + ((v.i >> 16) & 1u);
  return (u16)(r >> 16);
}

// ---------- length-sort machinery (descending): hist -> scan -> scatter ----------
__global__ void hist_kernel(const int* __restrict__ lens, int* __restrict__ hist) {
  int n = blockIdx.x * blockDim.x + threadIdx.x;
  if (n < NSEQ) atomicAdd(&hist[lens[n]], 1);
}
__global__ void scan_kernel(const int* __restrict__ hist, int* __restrict__ arr) {
  if (threadIdx.x == 0) {
    int s = 0;
    arr[21] = 0;
    for (int l = 20; l >= 1; --l) { s += hist[l]; arr[l] = s; }  // arr[l] = #(len >= l)
    arr[0] = NSEQ;
  }
}
__global__ void scatter_kernel(const int* __restrict__ lens, const int* __restrict__ arr,
                               int* __restrict__ cursor, int* __restrict__ perm,
                               int* __restrict__ lens_s) {
  int n = blockIdx.x * blockDim.x + threadIdx.x;
  if (n >= NSEQ) return;
  int len = lens[n];
  int pos = arr[len + 1] + atomicAdd(&cursor[len], 1);   // bucket base + offset
  perm[pos] = n;
  lens_s[pos] = len;
}

// ---------- embeddings (sorted order): embT[t][pos][EMBP] bf16 ----------
__global__ __launch_bounds__(320) void embed_kernel(
    const int* __restrict__ opt, const float* __restrict__ Wemb,
    const int* __restrict__ perm, u16* __restrict__ embT) {
  int pos = blockIdx.x;
  int orig = perm[pos];
  int e = threadIdx.x;
#pragma unroll 4
  for (int t = 0; t < TMAX; ++t) {
    int tok = opt[orig * TMAX + t];
    float v = 0.f;
    if (e < EMB && tok != 0) v = Wemb[(size_t)tok * EMB + e];
    embT[((size_t)t * NSEQ + pos) * EMBP + e] = f2bf(v);
  }
}

// ---------- weight repack to bf16, concatenated [ih | hh] along K ----------
__global__ void prep_w0(const float* __restrict__ wih, const float* __restrict__ whh,
                        u16* __restrict__ W) {
  for (int idx = blockIdx.x * blockDim.x + threadIdx.x; idx < 2048 * KL0;
       idx += gridDim.x * blockDim.x) {
    int o = idx / KL0, c = idx % KL0;
    float v;
    if (c < EMB) v = wih[o * EMB + c];
    else if (c < EMBP) v = 0.f;
    else v = whh[o * HID + (c - EMBP)];
    W[idx] = f2bf(v);
  }
}
__global__ void prep_w1(const float* __restrict__ wih, const float* __restrict__ whh,
                        u16* __restrict__ W) {
  for (int idx = blockIdx.x * blockDim.x + threadIdx.x; idx < 2048 * KL1;
       idx += gridDim.x * blockDim.x) {
    int o = idx / KL1, c = idx % KL1;
    float v = (c < HID) ? wih[o * HID + c] : whh[o * HID + (c - HID)];
    W[idx] = f2bf(v);
  }
}
__global__ void prep_bias(const float* __restrict__ a, const float* __restrict__ b,
                          float* __restrict__ o) {
  int i = blockIdx.x * blockDim.x + threadIdx.x;
  if (i < 2048) o[i] = a[i] + b[i];
}

// ---------- fused GEMM + LSTM cell step: 8-phase 256x256, length-pruned ----------
// Rows are length-sorted DESC; block exits if rowBlk >= arr[t] (= #rows len>=t).
// Boundary rows with len==t take the act=false copy path (hysteresis keeps the
// frozen-h carry in the double buffer race-free). All next-tile staging issues in
// p0/p1 so the end-of-tile vmcnt(0) waits only for loads >=2 phases old.
__global__ __launch_bounds__(512, 2) void lstm_step(
    const u16* __restrict__ segA0, int strideA0, int K0,
    const u16* __restrict__ segA1,                 // [NSEQ][HID] bf16, h_old
    const u16* __restrict__ Wcat, int Ktot, int nkt,
    const float* __restrict__ biasc,
    u16* __restrict__ h_new, float* __restrict__ c_state,
    float* __restrict__ hfB,                       // f32 h (layer1 only), single buffer
    const int* __restrict__ lens, const int* __restrict__ activeArr, int t) {
  const int activeCnt = activeArr[t];
  // bijective XCD remap: 200 blocks, 8 XCDs, 25 consecutive wgids per XCD
  const int orig = blockIdx.x;
  const int wgid = (orig & 7) * 25 + (orig >> 3);
  const int rowBlk = (wgid >> 3) * 256;
  const int hblk = (wgid & 7) * 64;
  if (rowBlk >= activeCnt) return;                 // uniform exit: dead row tile

  __shared__ __align__(16) u16 Abuf[2][256 * 64];
  __shared__ __align__(16) u16 Bbuf[2][256 * 64];
  const int tid = threadIdx.x;
  const int wave = tid >> 6, lane = tid & 63;
  const int l15 = lane & 15, l4 = lane >> 4;
  const int mw = wave >> 1, nw = wave & 1;

  const int srow = tid >> 3;
  const int sslot = (tid & 7) ^ (srow & 7);        // pre-swizzled source 16B slot

  auto stageA = [&](int sel, int hb, int kt) {
    const int kbase = kt * 64;
    const bool s1 = kbase >= K0;
#pragma unroll
    for (int i = 0; i < 2; ++i) {
      int lrow = hb * 128 + i * 64 + srow;
      int gr = rowBlk + lrow;
      const u16* src = s1 ? (segA1 + (size_t)gr * HID + (kbase - K0) + sslot * 8)
                          : (segA0 + (size_t)gr * strideA0 + kbase + sslot * 8);
      __builtin_amdgcn_global_load_lds(
          (const __attribute__((address_space(1))) void*)src,
          (__attribute__((address_space(3))) void*)(&Abuf[sel][lrow * 64 + (tid & 7) * 8]),
          16, 0, 0);
    }
  };
  auto stageB = [&](int sel, int hb, int kt) {
    const int kbase = kt * 64;
#pragma unroll
    for (int i = 0; i < 2; ++i) {
      int lrow = hb * 128 + i * 64 + srow;
      int g = hb * 2 + i;
      const u16* src = Wcat + (size_t)(g * HID + hblk + srow) * Ktot + kbase + sslot * 8;
      __builtin_amdgcn_global_load_lds(
          (const __attribute__((address_space(1))) void*)src,
          (__attribute__((address_space(3))) void*)(&Bbuf[sel][lrow * 64 + (tid & 7) * 8]),
          16, 0, 0);
    }
  };

  f32x4 acc[4][8] = {};   // [m-frag][nf = gate*2 + hsub]
  bf16x8 a[2][2], bLo[4][2], bHi[4][2];

  auto rdA = [&](int sel, int mhalf) {
#pragma unroll
    for (int mf = 0; mf < 2; ++mf)
#pragma unroll
      for (int ks = 0; ks < 2; ++ks) {
        int row = mw * 64 + mhalf * 32 + mf * 16 + l15;
        int q = (ks * 4 + l4) ^ (row & 7);
        a[mf][ks] = *(const bf16x8*)&Abuf[sel][row * 64 + q * 8];
      }
  };
  auto rdB = [&](int sel, int nhalf, bf16x8 b[4][2]) {
#pragma unroll
    for (int f = 0; f < 4; ++f)
#pragma unroll
      for (int ks = 0; ks < 2; ++ks) {
        int nf = nhalf * 4 + f;
        int row = (nf >> 1) * 64 + nw * 32 + (nf & 1) * 16 + l15;
        int q = (ks * 4 + l4) ^ (row & 7);
        b[f][ks] = *(const bf16x8*)&Bbuf[sel][row * 64 + q * 8];
      }
  };
  auto mma = [&](bf16x8 b[4][2], int mhalf, int nhalf) {
    __builtin_amdgcn_s_setprio(1);
#pragma unroll
    for (int mf = 0; mf < 2; ++mf)
#pragma unroll
      for (int f = 0; f < 4; ++f)
#pragma unroll
        for (int ks = 0; ks < 2; ++ks)
          acc[mhalf * 2 + mf][nhalf * 4 + f] = __builtin_amdgcn_mfma_f32_16x16x32_bf16(
              a[mf][ks], b[f][ks], acc[mhalf * 2 + mf][nhalf * 4 + f], 0, 0, 0);
    __builtin_amdgcn_s_setprio(0);
  };

  // prologue: stage K-tile 0 fully, drain, barrier
  stageA(0, 0, 0); stageA(0, 1, 0); stageB(0, 0, 0); stageB(0, 1, 0);
  asm volatile("s_waitcnt vmcnt(0)" ::: "memory");
  __builtin_amdgcn_s_barrier();

  for (int kt = 0; kt < nkt; ++kt) {
    const int cur = kt & 1, nxt = cur ^ 1;
    const bool pf = (kt + 1 < nkt);
    // p0: all A staging for next tile issues here
    rdA(cur, 0); rdB(cur, 0, bLo);
    if (pf) { stageA(nxt, 0, kt + 1); stageA(nxt, 1, kt + 1); }
    __builtin_amdgcn_s_barrier();
    mma(bLo, 0, 0);
    __builtin_amdgcn_s_barrier();
    // p1: all B staging issues here
    rdB(cur, 1, bHi);
    if (pf) { stageB(nxt, 0, kt + 1); stageB(nxt, 1, kt + 1); }
    __builtin_amdgcn_s_barrier();
    mma(bHi, 0, 1);
    __builtin_amdgcn_s_barrier();
    // p2
    rdA(cur, 1);
    __builtin_amdgcn_s_barrier();
    mma(bHi, 1, 1);
    __builtin_amdgcn_s_barrier();
    // p3: loads are now >=2 phases old -> drain is cheap
    mma(bLo, 1, 0);
    if (pf) asm volatile("s_waitcnt vmcnt(0)" ::: "memory");
    __builtin_amdgcn_s_barrier();
  }

  // epilogue: LSTM cell. acc frag: col(l15)=h-sub, row=l4*4+jj.
#pragma unroll
  for (int hs = 0; hs < 2; ++hs) {
    const int uu = hblk + nw * 32 + hs * 16 + l15;
    const float bi = biasc[uu], bff = biasc[512 + uu];
    const float bgg = biasc[1024 + uu], bo = biasc[1536 + uu];
#pragma unroll
    for (int m = 0; m < 4; ++m) {
      const int rbase = rowBlk + mw * 64 + m * 16 + l4 * 4;
      const size_t cmi = (size_t)uu * NSEQ + rbase;   // column-major state index
      f32x4 co4 = *(const f32x4*)(c_state + cmi);
      int4 ln4 = *(const int4*)(lens + rbase);
      f32x4 cn4;
      u16 hstore[4];
#pragma unroll
      for (int jj = 0; jj < 4; ++jj) {
        float ip = acc[m][hs][jj] + bi;
        float fp = acc[m][2 + hs][jj] + bff;
        float gp = acc[m][4 + hs][jj] + bgg;
        float op = acc[m][6 + hs][jj] + bo;
        float co = co4[jj];
        float si = 1.f / (1.f + __expf(-ip));
        float sf = 1.f / (1.f + __expf(-fp));
        float so = 1.f / (1.f + __expf(-op));
        float tg = tanhf(gp);
        float cn = sf * co + si * tg;
        float hn = so * tanhf(cn);
        int len = (jj == 0) ? ln4.x : (jj == 1) ? ln4.y : (jj == 2) ? ln4.z : ln4.w;
        bool act = t < len;
        cn4[jj] = act ? cn : co;
        hstore[jj] = act ? f2bf(hn) : segA1[(size_t)(rbase + jj) * HID + uu];
        if (hfB && act) hfB[cmi + jj] = hn;          // exec-masked scalar store
      }
      *(f32x4*)(c_state + cmi) = cn4;
#pragma unroll
      for (int jj = 0; jj < 4; ++jj)
        h_new[(size_t)(rbase + jj) * HID + uu] = hstore[jj];
    }
  }
}

// ---------- scores: out[perm[pos]] = dot(hf[:,pos] (col-major), enc[orig/100,:]) ---
__global__ __launch_bounds__(256) void scores_kernel(
    const float* __restrict__ h2cm, const float* __restrict__ enc,
    const int* __restrict__ perm, float* __restrict__ out) {
  int pos = (blockIdx.x >> 1) * 256 + threadIdx.x;
  int uh = (blockIdx.x & 1) * 256;
  int orig = perm[pos];
  const float* ep = enc + (orig / 100) * HID + uh;
  float s = 0.f;
#pragma unroll 8
  for (int u = 0; u < 256; ++u) s += h2cm[(size_t)(uh + u) * NSEQ + pos] * ep[u];
  atomicAdd(&out[orig], s);
}

// ---------- relevance dtype detection (bool may arrive as u8/i32/i64/f32) ----------
__global__ void detect_kernel(const unsigned char* __restrict__ rel, int* __restrict__ flags) {
  int a = 0, bb = 0, z = 0;
  for (int i = blockIdx.x * blockDim.x + threadIdx.x; i < RELN; i += gridDim.x * blockDim.x) {
    if (rel[i]) {
      if (i & 3) a = 1; else z = 1;
      if (i & 4) bb = 1;
    }
  }
  if (a) atomicOr(&flags[0], 1);
  if (bb) atomicOr(&flags[1], 1);
  if (z) atomicOr(&flags[2], 1);
}

__global__ void qt_kernel(const void* __restrict__ rel, const int* __restrict__ qt_idx,
                          const int* __restrict__ opt_idx, const int* __restrict__ flags,
                          float* __restrict__ out) {
  int n = blockIdx.x * blockDim.x + threadIdx.x;
  if (n >= NSEQ) return;
  long long idx = (long long)qt_idx[n / 100] * NANS + opt_idx[n];
  int fa = flags[0], fb = flags[1], fz = flags[2];
  bool hit;
  if (fa && fz)       hit = ((const unsigned char*)rel)[idx] != 0;   // uint8 bool
  else if (fa)        hit = ((const float*)rel)[idx] != 0.f;         // float32
  else if (fb)        hit = ((const int*)rel)[idx] != 0;             // int32
  else                hit = ((const long long*)rel)[idx] != 0;       // int64
  out[NSEQ + n] = hit ? 1.f : 0.f;
}

extern "C" void kernel_launch(void* const* d_in, const int* in_sizes, int n_in,
                              void* d_out, int out_size, void* d_ws, size_t ws_size,
                              hipStream_t stream) {
  (void)in_sizes; (void)n_in; (void)out_size; (void)ws_size;
  const float* enc    = (const float*)d_in[0];
  const int*   opt    = (const int*)d_in[1];
  const int*   optlen = (const int*)d_in[2];
  const int*   qtidx  = (const int*)d_in[3];
  const int*   optidx = (const int*)d_in[4];
  const float* Wemb   = (const float*)d_in[5];
  const float* wih0   = (const float*)d_in[6];
  const float* whh0   = (const float*)d_in[7];
  const float* bih0   = (const float*)d_in[8];
  const float* bhh0   = (const float*)d_in[9];
  const float* wih1   = (const float*)d_in[10];
  const float* whh1   = (const float*)d_in[11];
  const float* bih1   = (const float*)d_in[12];
  const float* bhh1   = (const float*)d_in[13];
  const void*  rel    = d_in[14];
  float* out = (float*)d_out;

  char* ws = (char*)d_ws;
  size_t off = 0;
  auto alloc = [&](size_t bytes) -> void* {
    void* p = (void*)(ws + off);
    off += (bytes + 255) & ~(size_t)255;
    return p;
  };
  u16* embT   = (u16*)alloc((size_t)TMAX * NSEQ * EMBP * 2);
  u16* W0     = (u16*)alloc((size_t)2048 * KL0 * 2);
  u16* W1     = (u16*)alloc((size_t)2048 * KL1 * 2);
  float* bc0  = (float*)alloc(2048 * 4);
  float* bc1  = (float*)alloc(2048 * 4);
  u16* h0b[2] = { (u16*)alloc((size_t)NSEQ * HID * 2), (u16*)alloc((size_t)NSEQ * HID * 2) };
  u16* h1b[2] = { (u16*)alloc((size_t)NSEQ * HID * 2), (u16*)alloc((size_t)NSEQ * HID * 2) };
  float* c0   = (float*)alloc((size_t)NSEQ * HID * 4);
  float* c1   = (float*)alloc((size_t)NSEQ * HID * 4);
  float* hfB  = (float*)alloc((size_t)NSEQ * HID * 4);
  int* flags  = (int*)alloc(16);
  int* hist   = (int*)alloc(32 * 4);
  int* arr    = (int*)alloc(32 * 4);
  int* cursor = (int*)alloc(32 * 4);
  int* perm   = (int*)alloc(NSEQ * 4);
  int* lens_s = (int*)alloc(NSEQ * 4);

  hipMemsetAsync(h0b[0], 0, (size_t)NSEQ * HID * 2, stream);
  hipMemsetAsync(h1b[0], 0, (size_t)NSEQ * HID * 2, stream);
  hipMemsetAsync(c0, 0, (size_t)NSEQ * HID * 4, stream);
  hipMemsetAsync(c1, 0, (size_t)NSEQ * HID * 4, stream);
  hipMemsetAsync(flags, 0, 16, stream);
  hipMemsetAsync(hist, 0, 32 * 4, stream);
  hipMemsetAsync(cursor, 0, 32 * 4, stream);
  hipMemsetAsync(out, 0, (size_t)NSEQ * 4, stream);   // scores accumulated atomically

  hist_kernel<<<(NSEQ + 255) / 256, 256, 0, stream>>>(optlen, hist);
  scan_kernel<<<1, 64, 0, stream>>>(hist, arr);
  scatter_kernel<<<(NSEQ + 255) / 256, 256, 0, stream>>>(optlen, arr, cursor, perm, lens_s);
  embed_kernel<<<NSEQ, EMBP, 0, stream>>>(opt, Wemb, perm, embT);
  prep_w0<<<512, 256, 0, stream>>>(wih0, whh0, W0);
  prep_w1<<<512, 256, 0, stream>>>(wih1, whh1, W1);
  prep_bias<<<8, 256, 0, stream>>>(bih0, bhh0, bc0);
  prep_bias<<<8, 256, 0, stream>>>(bih1, bhh1, bc1);
  detect_kernel<<<256, 256, 0, stream>>>((const unsigned char*)rel, flags);

  for (int t = 0; t < TMAX; ++t) {
    int cur = t & 1, nxt = cur ^ 1;
    // layer 0: A = [emb_t | h0], B = W0cat
    lstm_step<<<200, 512, 0, stream>>>(
        embT + (size_t)t * NSEQ * EMBP, EMBP, EMBP,
        h0b[cur], W0, KL0, KL0 / 64, bc0,
        h0b[nxt], c0, nullptr, lens_s, arr, t);
    // layer 1: A = [h0_new | h1], B = W1cat
    lstm_step<<<200, 512, 0, stream>>>(
        h0b[nxt], HID, HID,
        h1b[cur], W1, KL1, KL1 / 64, bc1,
        h1b[nxt], c1, hfB, lens_s, arr, t);
  }

  scores_kernel<<<50, 256, 0, stream>>>(hfB, enc, perm, out);
  qt_kernel<<<(NSEQ + 255) / 256, 256, 0, stream>>>(rel, qtidx, optidx, flags, out);
}